// Round 12
// baseline (177.470 us; speedup 1.0000x reference)
//
#include <hip/hip_runtime.h>

typedef short s16x8 __attribute__((ext_vector_type(8)));
typedef float f32x4 __attribute__((ext_vector_type(4)));
typedef float f32x16 __attribute__((ext_vector_type(16)));

__device__ __forceinline__ unsigned short f2bf(float f) {
    unsigned int u = __float_as_uint(f);
    u += 0x7fff + ((u >> 16) & 1);   // RNE
    return (unsigned short)(u >> 16);
}
__device__ __forceinline__ float bf2f(unsigned short h) {
    return __uint_as_float(((unsigned int)h) << 16);
}
__device__ __forceinline__ f32x4 mfma16(s16x8 a, s16x8 b, f32x4 c) {
    return __builtin_amdgcn_mfma_f32_16x16x32_bf16(a, b, c, 0, 0, 0);
}
__device__ __forceinline__ f32x16 mfma32(s16x8 a, s16x8 b, f32x16 c) {
    return __builtin_amdgcn_mfma_f32_32x32x16_bf16(a, b, c, 0, 0, 0);
}
__device__ __forceinline__ void async16(const void* g, void* l) {
    __builtin_amdgcn_global_load_lds(
        (const __attribute__((address_space(1))) void*)g,
        (__attribute__((address_space(3))) void*)l, 16, 0, 0);
}

// ---------------------------------------------------------------------------
// fp32 -> bf16: x -> xb, wq|wk|wv -> wqkvb, wp -> wpb.
// ---------------------------------------------------------------------------
__global__ __launch_bounds__(256) void convert_all(
    const float* __restrict__ x,  const float* __restrict__ wq,
    const float* __restrict__ wk, const float* __restrict__ wv,
    const float* __restrict__ wp,
    unsigned short* __restrict__ xb, unsigned short* __restrict__ wqkvb,
    unsigned short* __restrict__ wpb)
{
    const size_t XN = 2048u * 1024u, WN = 1024u * 1024u;
    size_t e = ((size_t)blockIdx.x * 256 + threadIdx.x) * 4;
    const float* s; unsigned short* d;
    if (e < XN)                { s = x  + e;               d = xb    + e; }
    else if (e < XN + WN)      { s = wq + (e - XN);        d = wqkvb + (e - XN); }
    else if (e < XN + 2 * WN)  { s = wk + (e - XN - WN);   d = wqkvb + (e - XN); }
    else if (e < XN + 3 * WN)  { s = wv + (e - XN - 2*WN); d = wqkvb + (e - XN); }
    else                       { s = wp + (e - XN - 3*WN); d = wpb   + (e - XN - 3*WN); }
    float4 v = *(const float4*)s;
    ushort4 o;
    o.x = f2bf(v.x); o.y = f2bf(v.y); o.z = f2bf(v.z); o.w = f2bf(v.w);
    *(ushort4*)d = o;
}

// ---------------------------------------------------------------------------
// bf16 GEMM, BK=128: C[M x N] = A[M x 1024] * B[N x 1024]^T.
// BM x BN tile, 4 waves (2x2), global_load_lds width=16, 8 K-iterations.
// ---------------------------------------------------------------------------
template<int BM, int BN, int C32>
__global__ __launch_bounds__(256) void gemm_mfma(
    const unsigned short* __restrict__ A,
    const unsigned short* __restrict__ B,
    void* __restrict__ C, int Ntot)
{
    constexpr int MT = BM / 32, NT = BN / 32;
    __shared__ unsigned short As[BM * 128];
    __shared__ unsigned short Bs[BN * 128];

    const int tid  = threadIdx.x;
    const int wave = tid >> 6, lane = tid & 63;
    const int l16  = lane & 15, quad = lane >> 4;
    const int m0   = blockIdx.y * BM, n0 = blockIdx.x * BN;
    const int wm   = (wave & 1) * (BM / 2), wn = (wave >> 1) * (BN / 2);

    const int r4 = lane >> 4;          // 0..3   (4-row group member)
    const int c8 = (lane & 15) * 8;    // 0..120 (k columns)

    f32x4 acc[MT][NT] = {};

    for (int k0 = 0; k0 < 1024; k0 += 128) {
        #pragma unroll
        for (int i = 0; i < BM / 16; i++) {
            int rg = wave * (BM / 16) + i;   // 4-row group
            async16(A + (size_t)(m0 + rg * 4 + r4) * 1024 + k0 + c8, &As[rg * 512]);
        }
        #pragma unroll
        for (int i = 0; i < BN / 16; i++) {
            int rg = wave * (BN / 16) + i;
            async16(B + (size_t)(n0 + rg * 4 + r4) * 1024 + k0 + c8, &Bs[rg * 512]);
        }
        __syncthreads();

        #pragma unroll
        for (int ks = 0; ks < 4; ks++) {
            s16x8 af[MT], bfr[NT];
            #pragma unroll
            for (int mt = 0; mt < MT; mt++)
                af[mt] = *(const s16x8*)&As[(wm + mt * 16 + l16) * 128 + ks * 32 + quad * 8];
            #pragma unroll
            for (int nt = 0; nt < NT; nt++)
                bfr[nt] = *(const s16x8*)&Bs[(wn + nt * 16 + l16) * 128 + ks * 32 + quad * 8];
            #pragma unroll
            for (int mt = 0; mt < MT; mt++)
                #pragma unroll
                for (int nt = 0; nt < NT; nt++)
                    acc[mt][nt] = mfma16(af[mt], bfr[nt], acc[mt][nt]);
        }
        __syncthreads();
    }

    #pragma unroll
    for (int mt = 0; mt < MT; mt++)
        #pragma unroll
        for (int nt = 0; nt < NT; nt++)
            #pragma unroll
            for (int r = 0; r < 4; r++) {
                int m = m0 + wm + mt * 16 + quad * 4 + r;
                int n = n0 + wn + nt * 16 + l16;
                size_t idx = (size_t)m * Ntot + n;
                if (C32) ((float*)C)[idx] = acc[mt][nt][r];
                else     ((unsigned short*)C)[idx] = f2bf(acc[mt][nt][r]);
            }
}

// ---------------------------------------------------------------------------
// RoPE in-place on qkv[2048][3072] (q at +0, k at +1024), verified convention.
// ---------------------------------------------------------------------------
__global__ __launch_bounds__(256) void rope_kernel(unsigned short* __restrict__ qkv)
{
    int idx = blockIdx.x * 256 + threadIdx.x;
    int i = idx & 31;
    int h = (idx >> 5) & 15;
    int n = idx >> 9;
    float ang = (float)n * exp2f((float)i * (-13.287712379549449f / 32.0f));
    float c, s;
    sincosf(ang, &c, &s);
    size_t base = (size_t)n * 3072 + h * 64 + i;
    float a0 = bf2f(qkv[base]), a1 = bf2f(qkv[base + 32]);
    qkv[base]      = f2bf(a0 * c + a1 * s);
    qkv[base + 32] = f2bf(a1 * c - a0 * s);
    float b0 = bf2f(qkv[base + 1024]), b1 = bf2f(qkv[base + 1056]);
    qkv[base + 1024] = f2bf(b0 * c + b1 * s);
    qkv[base + 1056] = f2bf(b1 * c - b0 * s);
}

// ---------------------------------------------------------------------------
// Split-K flash attention, 32x32x16 MFMA, operand-swapped QK.
// grid (16 qblk(128q), 16 heads, 4 ksplit(512k)). 4 waves x 32 queries.
// S^T = mfma(A=K, B=Q): q pinned to lane (n=lane&31), keys in regs ->
// lane-local row sums, b64-packed P writes. Unshifted softmax (|logit|<~3).
// R12 FIX: K staging copies 32 cols/thread (was 16 -> half of Ks was
// uninitialized LDS -> NaN).
// ---------------------------------------------------------------------------
__global__ __launch_bounds__(256, 4) void attn_part(
    const unsigned short* __restrict__ qkv,
    float* __restrict__ Opart, float* __restrict__ Lpart)
{
    const int h  = blockIdx.y;
    const int q0 = blockIdx.x * 128;
    const int ks = blockIdx.z;          // keys ks*512 .. +511
    const int tid  = threadIdx.x;
    const int wave = tid >> 6, lane = tid & 63;
    const int l32  = lane & 31, half = lane >> 5;

    __shared__ unsigned short Ks[64][72];      // [key][d]
    __shared__ unsigned short Vt[64][72];      // [d][key]
    __shared__ unsigned short Ps[4][32][72];   // per-wave P: [q][key]

    // Q as B-operand frags: n = q = l32, k(d) = c*16 + half*8 + j
    const unsigned short* qp = qkv + (size_t)(q0 + wave * 32 + l32) * 3072 + h * 64 + half * 8;
    s16x8 qb[4];
    #pragma unroll
    for (int c = 0; c < 4; c++)
        qb[c] = *(const s16x8*)(qp + c * 16);

    f32x16 o0 = {}, o1 = {};    // O[q][d]: d 0..31 / 32..63
    float lsum = 0.f;           // row sum for q = l32 (this half's keys)

    for (int t = 0; t < 8; t++) {
        const int kt = ks * 512 + t * 64;

        // ---- stage: threads 0-127 transpose V, threads 128-255 copy K ----
        if (tid < 128) {
            int g  = tid & 15;          // keys 4g..4g+3
            int d0 = (tid >> 4) * 8;    // 0..56
            const unsigned short* gv = qkv + (size_t)(kt + 4 * g) * 3072 + 2048 + h * 64 + d0;
            unsigned short a0[8], a1[8], a2[8], a3[8];
            *(uint4*)a0 = *(const uint4*)gv;
            *(uint4*)a1 = *(const uint4*)(gv + 3072);
            *(uint4*)a2 = *(const uint4*)(gv + 6144);
            *(uint4*)a3 = *(const uint4*)(gv + 9216);
            #pragma unroll
            for (int d = 0; d < 8; d++) {
                ushort4 w;
                w.x = a0[d]; w.y = a1[d]; w.z = a2[d]; w.w = a3[d];
                *(ushort4*)&Vt[d0 + d][4 * g] = w;
            }
        } else {
            int u = tid - 128;
            int key = u & 63;
            int dh = (u >> 6) * 32;     // 0 or 32; this thread covers dh..dh+31
            const unsigned short* gk = qkv + (size_t)(kt + key) * 3072 + 1024 + h * 64 + dh;
            const uint4* g4 = (const uint4*)gk;
            uint4 k0 = g4[0], k1 = g4[1], k2 = g4[2], k3 = g4[3];
            *(uint4*)&Ks[key][dh]      = k0;
            *(uint4*)&Ks[key][dh + 8]  = k1;
            *(uint4*)&Ks[key][dh + 16] = k2;
            *(uint4*)&Ks[key][dh + 24] = k3;
        }
        __syncthreads();

        // ---- S^T = K.Q^T (keys in regs), exp, lane row-sum, packed P write ----
        #pragma unroll
        for (int g = 0; g < 2; g++) {
            f32x16 s = {};
            #pragma unroll
            for (int c = 0; c < 4; c++) {
                s16x8 ka = *(const s16x8*)&Ks[g * 32 + l32][c * 16 + half * 8];
                s = mfma32(ka, qb[c], s);
            }
            // reg r -> key = 32g + (r&3) + 8*(r>>2) + 4*half, q = l32
            #pragma unroll
            for (int c = 0; c < 4; c++) {
                float e0 = __expf(s[4 * c + 0] * 0.125f);
                float e1 = __expf(s[4 * c + 1] * 0.125f);
                float e2 = __expf(s[4 * c + 2] * 0.125f);
                float e3 = __expf(s[4 * c + 3] * 0.125f);
                lsum += (e0 + e1) + (e2 + e3);
                ushort4 w;
                w.x = f2bf(e0); w.y = f2bf(e1); w.z = f2bf(e2); w.w = f2bf(e3);
                *(ushort4*)&Ps[wave][l32][g * 32 + c * 8 + half * 4] = w;
            }
        }

        // ---- O += P.V  (A=P[q][key], B=Vt[d][key]) ----
        #pragma unroll
        for (int c = 0; c < 4; c++) {
            s16x8 pa = *(const s16x8*)&Ps[wave][l32][c * 16 + half * 8];
            s16x8 v0 = *(const s16x8*)&Vt[l32][c * 16 + half * 8];
            s16x8 v1 = *(const s16x8*)&Vt[32 + l32][c * 16 + half * 8];
            o0 = mfma32(pa, v0, o0);
            o1 = mfma32(pa, v1, o1);
        }
        __syncthreads();
    }

    // combine the two key-halves of lsum (lanes l, l+32 share q = l32)
    lsum += __shfl_xor(lsum, 32, 64);

    // O: reg r -> q-row = (r&3)+8*(r>>2)+4*half, d = l32 / 32+l32
    const int mq = q0 + wave * 32;
    float* opBase = Opart + (size_t)ks * 2048 * 1024;
    #pragma unroll
    for (int r = 0; r < 16; r++) {
        int qr = (r & 3) + 8 * (r >> 2) + 4 * half;
        float* op = opBase + (size_t)(mq + qr) * 1024 + h * 64;
        op[l32]      = o0[r];
        op[32 + l32] = o1[r];
    }
    if (half == 0)
        Lpart[((size_t)ks * 2048 + mq + l32) * 16 + h] = lsum;
}

// ---------------------------------------------------------------------------
// Combine 4 split-K partials: ab = (sum n_i) / (sum l_i), bf16.
// ---------------------------------------------------------------------------
__global__ __launch_bounds__(256) void combine(
    const float* __restrict__ Opart, const float* __restrict__ Lpart,
    unsigned short* __restrict__ ab)
{
    size_t e = ((size_t)blockIdx.x * 256 + threadIdx.x) * 4;
    int tok = (int)(e >> 10);
    int h = (int)((e & 1023) >> 6);
    float l = 0.f;
    #pragma unroll
    for (int s = 0; s < 4; s++)
        l += Lpart[((size_t)s * 2048 + tok) * 16 + h];
    float inv = 1.0f / l;
    float4 acc = *(const float4*)(Opart + e);
    #pragma unroll
    for (int s = 1; s < 4; s++) {
        float4 n = *(const float4*)(Opart + (size_t)s * 2048 * 1024 + e);
        acc.x += n.x; acc.y += n.y; acc.z += n.z; acc.w += n.w;
    }
    ushort4 w;
    w.x = f2bf(acc.x * inv);
    w.y = f2bf(acc.y * inv);
    w.z = f2bf(acc.z * inv);
    w.w = f2bf(acc.w * inv);
    *(ushort4*)(ab + e) = w;
}

extern "C" void kernel_launch(void* const* d_in, const int* in_sizes, int n_in,
                              void* d_out, int out_size, void* d_ws, size_t ws_size,
                              hipStream_t stream)
{
    const float* x  = (const float*)d_in[0];
    const float* wq = (const float*)d_in[1];
    const float* wk = (const float*)d_in[2];
    const float* wv = (const float*)d_in[3];
    const float* wp = (const float*)d_in[4];

    unsigned short* xb    = (unsigned short*)d_ws;        // 2M shorts
    unsigned short* wqkvb = xb    + 2u * 1024 * 1024;     // 3M
    unsigned short* wpb   = wqkvb + 3u * 1024 * 1024;     // 1M
    unsigned short* qkv   = wpb   + 1u * 1024 * 1024;     // 6M
    unsigned short* ab    = qkv   + 2048u * 3072;         // 2M
    float* Opart = (float*)(ab + 2u * 1024 * 1024);       // 4 x 2048 x 1024 fp32
    float* Lpart = Opart + 4u * 2048 * 1024;              // 4 x 2048 x 16 fp32

    convert_all<<<6144, 256, 0, stream>>>(x, wq, wk, wv, wp, xb, wqkvb, wpb);
    gemm_mfma<128, 64, 0><<<dim3(48, 16), 256, 0, stream>>>(xb, wqkvb, qkv, 3072);
    rope_kernel<<<(2048 * 512) / 256, 256, 0, stream>>>(qkv);
    attn_part<<<dim3(16, 16, 4), 256, 0, stream>>>(qkv, Opart, Lpart);
    combine<<<2048, 256, 0, stream>>>(Opart, Lpart, ab);
    gemm_mfma<64, 64, 1><<<dim3(16, 32), 256, 0, stream>>>(ab, wpb, d_out, 1024);
}

// Round 13
// 163.133 us; speedup vs baseline: 1.0879x; 1.0879x over previous
//
#include <hip/hip_runtime.h>

typedef short s16x8 __attribute__((ext_vector_type(8)));
typedef float f32x4 __attribute__((ext_vector_type(4)));
typedef float f32x16 __attribute__((ext_vector_type(16)));

__device__ __forceinline__ unsigned short f2bf(float f) {
    unsigned int u = __float_as_uint(f);
    u += 0x7fff + ((u >> 16) & 1);   // RNE
    return (unsigned short)(u >> 16);
}
__device__ __forceinline__ float bf2f(unsigned short h) {
    return __uint_as_float(((unsigned int)h) << 16);
}
__device__ __forceinline__ f32x4 mfma16(s16x8 a, s16x8 b, f32x4 c) {
    return __builtin_amdgcn_mfma_f32_16x16x32_bf16(a, b, c, 0, 0, 0);
}
__device__ __forceinline__ f32x16 mfma32(s16x8 a, s16x8 b, f32x16 c) {
    return __builtin_amdgcn_mfma_f32_32x32x16_bf16(a, b, c, 0, 0, 0);
}
__device__ __forceinline__ void async16(const void* g, void* l) {
    __builtin_amdgcn_global_load_lds(
        (const __attribute__((address_space(1))) void*)g,
        (__attribute__((address_space(3))) void*)l, 16, 0, 0);
}

// ---------------------------------------------------------------------------
// fp32 -> bf16: x -> xb, wq|wk|wv -> wqkvb, wp -> wpb.
// ---------------------------------------------------------------------------
__global__ __launch_bounds__(256) void convert_all(
    const float* __restrict__ x,  const float* __restrict__ wq,
    const float* __restrict__ wk, const float* __restrict__ wv,
    const float* __restrict__ wp,
    unsigned short* __restrict__ xb, unsigned short* __restrict__ wqkvb,
    unsigned short* __restrict__ wpb)
{
    const size_t XN = 2048u * 1024u, WN = 1024u * 1024u;
    size_t e = ((size_t)blockIdx.x * 256 + threadIdx.x) * 4;
    const float* s; unsigned short* d;
    if (e < XN)                { s = x  + e;               d = xb    + e; }
    else if (e < XN + WN)      { s = wq + (e - XN);        d = wqkvb + (e - XN); }
    else if (e < XN + 2 * WN)  { s = wk + (e - XN - WN);   d = wqkvb + (e - XN); }
    else if (e < XN + 3 * WN)  { s = wv + (e - XN - 2*WN); d = wqkvb + (e - XN); }
    else                       { s = wp + (e - XN - 3*WN); d = wpb   + (e - XN - 3*WN); }
    float4 v = *(const float4*)s;
    ushort4 o;
    o.x = f2bf(v.x); o.y = f2bf(v.y); o.z = f2bf(v.z); o.w = f2bf(v.w);
    *(ushort4*)d = o;
}

// ---------------------------------------------------------------------------
// bf16 GEMM, BK=64 (m97 structure): C = A[M x 1024] * B[N x 1024]^T.
// BM x BN tile, 4 waves (2x2), global_load_lds width=16, unpadded LDS.
// blockIdx.z selects K-slice [z*kLen, (z+1)*kLen) and output slice z*cSlice.
// ---------------------------------------------------------------------------
template<int BM, int BN, int C32>
__global__ __launch_bounds__(256) void gemm_mfma(
    const unsigned short* __restrict__ A,
    const unsigned short* __restrict__ B,
    void* __restrict__ C, int Ntot, int kLen, size_t cSlice)
{
    constexpr int MT = BM / 32, NT = BN / 32;
    __shared__ unsigned short As[BM * 64];
    __shared__ unsigned short Bs[BN * 64];

    const int tid  = threadIdx.x;
    const int wave = tid >> 6, lane = tid & 63;
    const int l16  = lane & 15, quad = lane >> 4;
    const int m0   = blockIdx.y * BM, n0 = blockIdx.x * BN;
    const int kB   = blockIdx.z * kLen;
    const int wm   = (wave & 1) * (BM / 2), wn = (wave >> 1) * (BN / 2);

    const int srow8 = lane >> 3;        // 0..7 row within 8-row group
    const int scol  = (lane & 7) * 8;   // 0..56 col

    f32x4 acc[MT][NT] = {};

    for (int k0 = kB; k0 < kB + kLen; k0 += 64) {
        #pragma unroll
        for (int i = 0; i < BM / 32; i++) {
            int j = wave * (BM / 32) + i;    // 8-row group, 0..BM/8-1
            async16(A + (size_t)(m0 + j * 8 + srow8) * 1024 + k0 + scol, &As[j * 512]);
        }
        #pragma unroll
        for (int i = 0; i < BN / 32; i++) {
            int j = wave * (BN / 32) + i;
            async16(B + (size_t)(n0 + j * 8 + srow8) * 1024 + k0 + scol, &Bs[j * 512]);
        }
        __syncthreads();

        #pragma unroll
        for (int ks = 0; ks < 2; ks++) {
            s16x8 af[MT], bfr[NT];
            #pragma unroll
            for (int mt = 0; mt < MT; mt++)
                af[mt] = *(const s16x8*)&As[(wm + mt * 16 + l16) * 64 + ks * 32 + quad * 8];
            #pragma unroll
            for (int nt = 0; nt < NT; nt++)
                bfr[nt] = *(const s16x8*)&Bs[(wn + nt * 16 + l16) * 64 + ks * 32 + quad * 8];
            #pragma unroll
            for (int mt = 0; mt < MT; mt++)
                #pragma unroll
                for (int nt = 0; nt < NT; nt++)
                    acc[mt][nt] = mfma16(af[mt], bfr[nt], acc[mt][nt]);
        }
        __syncthreads();
    }

    // C/D layout: col = lane&15, row = quad*4 + reg
    #pragma unroll
    for (int mt = 0; mt < MT; mt++)
        #pragma unroll
        for (int nt = 0; nt < NT; nt++)
            #pragma unroll
            for (int r = 0; r < 4; r++) {
                int m = m0 + wm + mt * 16 + quad * 4 + r;
                int n = n0 + wn + nt * 16 + l16;
                size_t idx = (size_t)blockIdx.z * cSlice + (size_t)m * Ntot + n;
                if (C32) ((float*)C)[idx] = acc[mt][nt][r];
                else     ((unsigned short*)C)[idx] = f2bf(acc[mt][nt][r]);
            }
}

// ---------------------------------------------------------------------------
// Sum 2 fp32 split-K partials -> fp32 d_out.
// ---------------------------------------------------------------------------
__global__ __launch_bounds__(256) void reduce_proj(
    const float* __restrict__ P, float* __restrict__ out)
{
    size_t e = ((size_t)blockIdx.x * 256 + threadIdx.x) * 4;
    float4 a = *(const float4*)(P + e);
    float4 b = *(const float4*)(P + (size_t)2048 * 1024 + e);
    float4 o;
    o.x = a.x + b.x; o.y = a.y + b.y; o.z = a.z + b.z; o.w = a.w + b.w;
    *(float4*)(out + e) = o;
}

// ---------------------------------------------------------------------------
// RoPE in-place on qkv[2048][3072] (q at +0, k at +1024), verified convention.
// ---------------------------------------------------------------------------
__global__ __launch_bounds__(256) void rope_kernel(unsigned short* __restrict__ qkv)
{
    int idx = blockIdx.x * 256 + threadIdx.x;
    int i = idx & 31;
    int h = (idx >> 5) & 15;
    int n = idx >> 9;
    float ang = (float)n * exp2f((float)i * (-13.287712379549449f / 32.0f));
    float c, s;
    sincosf(ang, &c, &s);
    size_t base = (size_t)n * 3072 + h * 64 + i;
    float a0 = bf2f(qkv[base]), a1 = bf2f(qkv[base + 32]);
    qkv[base]      = f2bf(a0 * c + a1 * s);
    qkv[base + 32] = f2bf(a1 * c - a0 * s);
    float b0 = bf2f(qkv[base + 1024]), b1 = bf2f(qkv[base + 1056]);
    qkv[base + 1024] = f2bf(b0 * c + b1 * s);
    qkv[base + 1056] = f2bf(b1 * c - b0 * s);
}

// ---------------------------------------------------------------------------
// Split-K flash attention, 32x32x16 MFMA, operand-swapped QK (round-12,
// verified). grid (16 qblk(128q), 16 heads, 4 ksplit(512k)).
// ---------------------------------------------------------------------------
__global__ __launch_bounds__(256, 4) void attn_part(
    const unsigned short* __restrict__ qkv,
    float* __restrict__ Opart, float* __restrict__ Lpart)
{
    const int h  = blockIdx.y;
    const int q0 = blockIdx.x * 128;
    const int ks = blockIdx.z;          // keys ks*512 .. +511
    const int tid  = threadIdx.x;
    const int wave = tid >> 6, lane = tid & 63;
    const int l32  = lane & 31, half = lane >> 5;

    __shared__ unsigned short Ks[64][72];      // [key][d]
    __shared__ unsigned short Vt[64][72];      // [d][key]
    __shared__ unsigned short Ps[4][32][72];   // per-wave P: [q][key]

    // Q as B-operand frags: n = q = l32, k(d) = c*16 + half*8 + j
    const unsigned short* qp = qkv + (size_t)(q0 + wave * 32 + l32) * 3072 + h * 64 + half * 8;
    s16x8 qb[4];
    #pragma unroll
    for (int c = 0; c < 4; c++)
        qb[c] = *(const s16x8*)(qp + c * 16);

    f32x16 o0 = {}, o1 = {};    // O[q][d]: d 0..31 / 32..63
    float lsum = 0.f;

    for (int t = 0; t < 8; t++) {
        const int kt = ks * 512 + t * 64;

        if (tid < 128) {
            int g  = tid & 15;          // keys 4g..4g+3
            int d0 = (tid >> 4) * 8;    // 0..56
            const unsigned short* gv = qkv + (size_t)(kt + 4 * g) * 3072 + 2048 + h * 64 + d0;
            unsigned short a0[8], a1[8], a2[8], a3[8];
            *(uint4*)a0 = *(const uint4*)gv;
            *(uint4*)a1 = *(const uint4*)(gv + 3072);
            *(uint4*)a2 = *(const uint4*)(gv + 6144);
            *(uint4*)a3 = *(const uint4*)(gv + 9216);
            #pragma unroll
            for (int d = 0; d < 8; d++) {
                ushort4 w;
                w.x = a0[d]; w.y = a1[d]; w.z = a2[d]; w.w = a3[d];
                *(ushort4*)&Vt[d0 + d][4 * g] = w;
            }
        } else {
            int u = tid - 128;
            int key = u & 63;
            int dh = (u >> 6) * 32;     // covers dh..dh+31
            const unsigned short* gk = qkv + (size_t)(kt + key) * 3072 + 1024 + h * 64 + dh;
            const uint4* g4 = (const uint4*)gk;
            uint4 k0 = g4[0], k1 = g4[1], k2 = g4[2], k3 = g4[3];
            *(uint4*)&Ks[key][dh]      = k0;
            *(uint4*)&Ks[key][dh + 8]  = k1;
            *(uint4*)&Ks[key][dh + 16] = k2;
            *(uint4*)&Ks[key][dh + 24] = k3;
        }
        __syncthreads();

        // ---- S^T = K.Q^T, exp, lane row-sum, packed P write ----
        #pragma unroll
        for (int g = 0; g < 2; g++) {
            f32x16 s = {};
            #pragma unroll
            for (int c = 0; c < 4; c++) {
                s16x8 ka = *(const s16x8*)&Ks[g * 32 + l32][c * 16 + half * 8];
                s = mfma32(ka, qb[c], s);
            }
            // reg r -> key = 32g + (r&3) + 8*(r>>2) + 4*half, q = l32
            #pragma unroll
            for (int c = 0; c < 4; c++) {
                float e0 = __expf(s[4 * c + 0] * 0.125f);
                float e1 = __expf(s[4 * c + 1] * 0.125f);
                float e2 = __expf(s[4 * c + 2] * 0.125f);
                float e3 = __expf(s[4 * c + 3] * 0.125f);
                lsum += (e0 + e1) + (e2 + e3);
                ushort4 w;
                w.x = f2bf(e0); w.y = f2bf(e1); w.z = f2bf(e2); w.w = f2bf(e3);
                *(ushort4*)&Ps[wave][l32][g * 32 + c * 8 + half * 4] = w;
            }
        }

        // ---- O += P.V ----
        #pragma unroll
        for (int c = 0; c < 4; c++) {
            s16x8 pa = *(const s16x8*)&Ps[wave][l32][c * 16 + half * 8];
            s16x8 v0 = *(const s16x8*)&Vt[l32][c * 16 + half * 8];
            s16x8 v1 = *(const s16x8*)&Vt[32 + l32][c * 16 + half * 8];
            o0 = mfma32(pa, v0, o0);
            o1 = mfma32(pa, v1, o1);
        }
        __syncthreads();
    }

    lsum += __shfl_xor(lsum, 32, 64);

    const int mq = q0 + wave * 32;
    float* opBase = Opart + (size_t)ks * 2048 * 1024;
    #pragma unroll
    for (int r = 0; r < 16; r++) {
        int qr = (r & 3) + 8 * (r >> 2) + 4 * half;
        float* op = opBase + (size_t)(mq + qr) * 1024 + h * 64;
        op[l32]      = o0[r];
        op[32 + l32] = o1[r];
    }
    if (half == 0)
        Lpart[((size_t)ks * 2048 + mq + l32) * 16 + h] = lsum;
}

// ---------------------------------------------------------------------------
// Combine 4 split-K partials: ab = (sum n_i) / (sum l_i), bf16.
// ---------------------------------------------------------------------------
__global__ __launch_bounds__(256) void combine(
    const float* __restrict__ Opart, const float* __restrict__ Lpart,
    unsigned short* __restrict__ ab)
{
    size_t e = ((size_t)blockIdx.x * 256 + threadIdx.x) * 4;
    int tok = (int)(e >> 10);
    int h = (int)((e & 1023) >> 6);
    float l = 0.f;
    #pragma unroll
    for (int s = 0; s < 4; s++)
        l += Lpart[((size_t)s * 2048 + tok) * 16 + h];
    float inv = 1.0f / l;
    float4 acc = *(const float4*)(Opart + e);
    #pragma unroll
    for (int s = 1; s < 4; s++) {
        float4 n = *(const float4*)(Opart + (size_t)s * 2048 * 1024 + e);
        acc.x += n.x; acc.y += n.y; acc.z += n.z; acc.w += n.w;
    }
    ushort4 w;
    w.x = f2bf(acc.x * inv);
    w.y = f2bf(acc.y * inv);
    w.z = f2bf(acc.z * inv);
    w.w = f2bf(acc.w * inv);
    *(ushort4*)(ab + e) = w;
}

extern "C" void kernel_launch(void* const* d_in, const int* in_sizes, int n_in,
                              void* d_out, int out_size, void* d_ws, size_t ws_size,
                              hipStream_t stream)
{
    const float* x  = (const float*)d_in[0];
    const float* wq = (const float*)d_in[1];
    const float* wk = (const float*)d_in[2];
    const float* wv = (const float*)d_in[3];
    const float* wp = (const float*)d_in[4];

    unsigned short* xb    = (unsigned short*)d_ws;        // 2M shorts
    unsigned short* wqkvb = xb    + 2u * 1024 * 1024;     // 3M
    unsigned short* wpb   = wqkvb + 3u * 1024 * 1024;     // 1M
    unsigned short* qkv   = wpb   + 1u * 1024 * 1024;     // 6M
    unsigned short* ab    = qkv   + 2048u * 3072;         // 2M
    float* Opart    = (float*)(ab + 2u * 1024 * 1024);    // 4 x 2048 x 1024 fp32
    float* Lpart    = Opart + 4u * 2048 * 1024;           // 4 x 2048 x 16 fp32
    float* projPart = Lpart + 4u * 2048 * 16;             // 2 x 2048 x 1024 fp32

    convert_all<<<6144, 256, 0, stream>>>(x, wq, wk, wv, wp, xb, wqkvb, wpb);
    // qkv: 128x128 tile, full K
    gemm_mfma<128, 128, 0><<<dim3(24, 16, 1), 256, 0, stream>>>(
        xb, wqkvb, qkv, 3072, 1024, 0);
    rope_kernel<<<(2048 * 512) / 256, 256, 0, stream>>>(qkv);
    attn_part<<<dim3(16, 16, 4), 256, 0, stream>>>(qkv, Opart, Lpart);
    combine<<<2048, 256, 0, stream>>>(Opart, Lpart, ab);
    // proj: 64x64 tile, split-K x2 -> fp32 partials, then reduce
    gemm_mfma<64, 64, 1><<<dim3(16, 32, 2), 256, 0, stream>>>(
        ab, wpb, projPart, 1024, 512, (size_t)2048 * 1024);
    reduce_proj<<<2048, 256, 0, stream>>>(projPart, (float*)d_out);
}

// Round 14
// 154.978 us; speedup vs baseline: 1.1451x; 1.0526x over previous
//
#include <hip/hip_runtime.h>

typedef short s16x8 __attribute__((ext_vector_type(8)));
typedef float f32x4 __attribute__((ext_vector_type(4)));
typedef float f32x16 __attribute__((ext_vector_type(16)));

__device__ __forceinline__ unsigned short f2bf(float f) {
    unsigned int u = __float_as_uint(f);
    u += 0x7fff + ((u >> 16) & 1);   // RNE
    return (unsigned short)(u >> 16);
}
__device__ __forceinline__ float bf2f(unsigned short h) {
    return __uint_as_float(((unsigned int)h) << 16);
}
__device__ __forceinline__ f32x4 mfma16(s16x8 a, s16x8 b, f32x4 c) {
    return __builtin_amdgcn_mfma_f32_16x16x32_bf16(a, b, c, 0, 0, 0);
}
__device__ __forceinline__ f32x16 mfma32(s16x8 a, s16x8 b, f32x16 c) {
    return __builtin_amdgcn_mfma_f32_32x32x16_bf16(a, b, c, 0, 0, 0);
}
__device__ __forceinline__ void async16(const void* g, void* l) {
    __builtin_amdgcn_global_load_lds(
        (const __attribute__((address_space(1))) void*)g,
        (__attribute__((address_space(3))) void*)l, 16, 0, 0);
}

#define ROPE_C (-13.287712379549449f / 32.0f)

// ---------------------------------------------------------------------------
// fp32 -> bf16: x -> xb, wq|wk|wv -> wqkvb, wp -> wpb.
// ---------------------------------------------------------------------------
__global__ __launch_bounds__(256) void convert_all(
    const float* __restrict__ x,  const float* __restrict__ wq,
    const float* __restrict__ wk, const float* __restrict__ wv,
    const float* __restrict__ wp,
    unsigned short* __restrict__ xb, unsigned short* __restrict__ wqkvb,
    unsigned short* __restrict__ wpb)
{
    const size_t XN = 2048u * 1024u, WN = 1024u * 1024u;
    size_t e = ((size_t)blockIdx.x * 256 + threadIdx.x) * 4;
    const float* s; unsigned short* d;
    if (e < XN)                { s = x  + e;               d = xb    + e; }
    else if (e < XN + WN)      { s = wq + (e - XN);        d = wqkvb + (e - XN); }
    else if (e < XN + 2 * WN)  { s = wk + (e - XN - WN);   d = wqkvb + (e - XN); }
    else if (e < XN + 3 * WN)  { s = wv + (e - XN - 2*WN); d = wqkvb + (e - XN); }
    else                       { s = wp + (e - XN - 3*WN); d = wpb   + (e - XN - 3*WN); }
    float4 v = *(const float4*)s;
    ushort4 o;
    o.x = f2bf(v.x); o.y = f2bf(v.y); o.z = f2bf(v.z); o.w = f2bf(v.w);
    *(ushort4*)d = o;
}

// ---------------------------------------------------------------------------
// bf16 GEMM (m97 structure, BK=64): C = A[M x 1024] * B[N x 1024]^T.
// BM x BN tile, 4 waves (2x2), wave tile (BM/2)x(BN/2), global_load_lds.
// ROPE=1 (requires BN=128): n-blocks < 16 are q/k sections of the fused qkv
// output; wave tile = 64 cols = one head; pair (i,i+32) = (acc[..][nt],
// acc[..][nt+2]) in the SAME lane -> in-register rotation (verified
// convention: q'[i] = q[i]c + q[i+32]s ; q'[i+32] = q[i+32]c - q[i]s).
// ---------------------------------------------------------------------------
template<int BM, int BN, int C32, int ROPE>
__global__ __launch_bounds__(256) void gemm_mfma(
    const unsigned short* __restrict__ A,
    const unsigned short* __restrict__ B,
    void* __restrict__ C, int Ntot)
{
    constexpr int MT = BM / 32, NT = BN / 32;
    __shared__ unsigned short As[BM * 64];
    __shared__ unsigned short Bs[BN * 64];

    const int tid  = threadIdx.x;
    const int wave = tid >> 6, lane = tid & 63;
    const int l16  = lane & 15, quad = lane >> 4;
    const int m0   = blockIdx.y * BM, n0 = blockIdx.x * BN;
    const int wm   = (wave & 1) * (BM / 2), wn = (wave >> 1) * (BN / 2);

    const int srow8 = lane >> 3;        // 0..7
    const int scol  = (lane & 7) * 8;   // 0..56

    f32x4 acc[MT][NT] = {};

    for (int k0 = 0; k0 < 1024; k0 += 64) {
        #pragma unroll
        for (int i = 0; i < BM / 32; i++) {
            int j = wave * (BM / 32) + i;
            async16(A + (size_t)(m0 + j * 8 + srow8) * 1024 + k0 + scol, &As[j * 512]);
        }
        #pragma unroll
        for (int i = 0; i < BN / 32; i++) {
            int j = wave * (BN / 32) + i;
            async16(B + (size_t)(n0 + j * 8 + srow8) * 1024 + k0 + scol, &Bs[j * 512]);
        }
        __syncthreads();

        #pragma unroll
        for (int ks = 0; ks < 2; ks++) {
            s16x8 af[MT], bfr[NT];
            #pragma unroll
            for (int mt = 0; mt < MT; mt++)
                af[mt] = *(const s16x8*)&As[(wm + mt * 16 + l16) * 64 + ks * 32 + quad * 8];
            #pragma unroll
            for (int nt = 0; nt < NT; nt++)
                bfr[nt] = *(const s16x8*)&Bs[(wn + nt * 16 + l16) * 64 + ks * 32 + quad * 8];
            #pragma unroll
            for (int mt = 0; mt < MT; mt++)
                #pragma unroll
                for (int nt = 0; nt < NT; nt++)
                    acc[mt][nt] = mfma16(af[mt], bfr[nt], acc[mt][nt]);
        }
        __syncthreads();
    }

    // Fused RoPE on q/k sections (in-register, fp32, before bf16 store)
    if constexpr (ROPE) {
        if (n0 < 2048) {
            #pragma unroll
            for (int mt = 0; mt < MT; mt++)
                #pragma unroll
                for (int r = 0; r < 4; r++) {
                    int m = m0 + wm + mt * 16 + quad * 4 + r;   // token
                    #pragma unroll
                    for (int nt = 0; nt < 2; nt++) {
                        int i = nt * 16 + l16;                  // 0..31 in head
                        float ang = (float)m * exp2f((float)i * ROPE_C);
                        float c, s;
                        sincosf(ang, &c, &s);
                        float e0 = acc[mt][nt][r], e1 = acc[mt][nt + 2][r];
                        acc[mt][nt][r]     = e0 * c + e1 * s;
                        acc[mt][nt + 2][r] = e1 * c - e0 * s;
                    }
                }
        }
    }

    // C/D layout: col = lane&15, row = quad*4 + reg
    #pragma unroll
    for (int mt = 0; mt < MT; mt++)
        #pragma unroll
        for (int nt = 0; nt < NT; nt++)
            #pragma unroll
            for (int r = 0; r < 4; r++) {
                int m = m0 + wm + mt * 16 + quad * 4 + r;
                int n = n0 + wn + nt * 16 + l16;
                size_t idx = (size_t)m * Ntot + n;
                if (C32) ((float*)C)[idx] = acc[mt][nt][r];
                else     ((unsigned short*)C)[idx] = f2bf(acc[mt][nt][r]);
            }
}

// ---------------------------------------------------------------------------
// Split-K flash attention, 32x32x16 MFMA, operand-swapped QK (verified r12).
// grid (16 qblk(128q), 16 heads, 4 ksplit(512k)). bf16 numerator partials.
// ---------------------------------------------------------------------------
__global__ __launch_bounds__(256, 4) void attn_part(
    const unsigned short* __restrict__ qkv,
    unsigned short* __restrict__ Opart, float* __restrict__ Lpart)
{
    const int h  = blockIdx.y;
    const int q0 = blockIdx.x * 128;
    const int ks = blockIdx.z;          // keys ks*512 .. +511
    const int tid  = threadIdx.x;
    const int wave = tid >> 6, lane = tid & 63;
    const int l32  = lane & 31, half = lane >> 5;

    __shared__ unsigned short Ks[64][72];      // [key][d]
    __shared__ unsigned short Vt[64][72];      // [d][key]
    __shared__ unsigned short Ps[4][32][72];   // per-wave P: [q][key]

    const unsigned short* qp = qkv + (size_t)(q0 + wave * 32 + l32) * 3072 + h * 64 + half * 8;
    s16x8 qb[4];
    #pragma unroll
    for (int c = 0; c < 4; c++)
        qb[c] = *(const s16x8*)(qp + c * 16);

    f32x16 o0 = {}, o1 = {};
    float lsum = 0.f;

    for (int t = 0; t < 8; t++) {
        const int kt = ks * 512 + t * 64;

        if (tid < 128) {
            int g  = tid & 15;
            int d0 = (tid >> 4) * 8;
            const unsigned short* gv = qkv + (size_t)(kt + 4 * g) * 3072 + 2048 + h * 64 + d0;
            unsigned short a0[8], a1[8], a2[8], a3[8];
            *(uint4*)a0 = *(const uint4*)gv;
            *(uint4*)a1 = *(const uint4*)(gv + 3072);
            *(uint4*)a2 = *(const uint4*)(gv + 6144);
            *(uint4*)a3 = *(const uint4*)(gv + 9216);
            #pragma unroll
            for (int d = 0; d < 8; d++) {
                ushort4 w;
                w.x = a0[d]; w.y = a1[d]; w.z = a2[d]; w.w = a3[d];
                *(ushort4*)&Vt[d0 + d][4 * g] = w;
            }
        } else {
            int u = tid - 128;
            int key = u & 63;
            int dh = (u >> 6) * 32;
            const unsigned short* gk = qkv + (size_t)(kt + key) * 3072 + 1024 + h * 64 + dh;
            const uint4* g4 = (const uint4*)gk;
            uint4 k0 = g4[0], k1 = g4[1], k2 = g4[2], k3 = g4[3];
            *(uint4*)&Ks[key][dh]      = k0;
            *(uint4*)&Ks[key][dh + 8]  = k1;
            *(uint4*)&Ks[key][dh + 16] = k2;
            *(uint4*)&Ks[key][dh + 24] = k3;
        }
        __syncthreads();

        #pragma unroll
        for (int g = 0; g < 2; g++) {
            f32x16 s = {};
            #pragma unroll
            for (int c = 0; c < 4; c++) {
                s16x8 ka = *(const s16x8*)&Ks[g * 32 + l32][c * 16 + half * 8];
                s = mfma32(ka, qb[c], s);
            }
            #pragma unroll
            for (int c = 0; c < 4; c++) {
                float e0 = __expf(s[4 * c + 0] * 0.125f);
                float e1 = __expf(s[4 * c + 1] * 0.125f);
                float e2 = __expf(s[4 * c + 2] * 0.125f);
                float e3 = __expf(s[4 * c + 3] * 0.125f);
                lsum += (e0 + e1) + (e2 + e3);
                ushort4 w;
                w.x = f2bf(e0); w.y = f2bf(e1); w.z = f2bf(e2); w.w = f2bf(e3);
                *(ushort4*)&Ps[wave][l32][g * 32 + c * 8 + half * 4] = w;
            }
        }

        #pragma unroll
        for (int c = 0; c < 4; c++) {
            s16x8 pa = *(const s16x8*)&Ps[wave][l32][c * 16 + half * 8];
            s16x8 v0 = *(const s16x8*)&Vt[l32][c * 16 + half * 8];
            s16x8 v1 = *(const s16x8*)&Vt[32 + l32][c * 16 + half * 8];
            o0 = mfma32(pa, v0, o0);
            o1 = mfma32(pa, v1, o1);
        }
        __syncthreads();
    }

    lsum += __shfl_xor(lsum, 32, 64);

    const int mq = q0 + wave * 32;
    unsigned short* opBase = Opart + (size_t)ks * 2048 * 1024;
    #pragma unroll
    for (int r = 0; r < 16; r++) {
        int qr = (r & 3) + 8 * (r >> 2) + 4 * half;
        unsigned short* op = opBase + (size_t)(mq + qr) * 1024 + h * 64;
        op[l32]      = f2bf(o0[r]);
        op[32 + l32] = f2bf(o1[r]);
    }
    if (half == 0)
        Lpart[((size_t)ks * 2048 + mq + l32) * 16 + h] = lsum;
}

// ---------------------------------------------------------------------------
// Combine 4 bf16 split-K partials: ab = (sum n_i) / (sum l_i), bf16.
// ---------------------------------------------------------------------------
__global__ __launch_bounds__(256) void combine(
    const unsigned short* __restrict__ Opart, const float* __restrict__ Lpart,
    unsigned short* __restrict__ ab)
{
    size_t e = ((size_t)blockIdx.x * 256 + threadIdx.x) * 4;
    int tok = (int)(e >> 10);
    int h = (int)((e & 1023) >> 6);
    float l = 0.f;
    #pragma unroll
    for (int s = 0; s < 4; s++)
        l += Lpart[((size_t)s * 2048 + tok) * 16 + h];
    float inv = 1.0f / l;
    float a0 = 0.f, a1 = 0.f, a2 = 0.f, a3 = 0.f;
    #pragma unroll
    for (int s = 0; s < 4; s++) {
        ushort4 n = *(const ushort4*)(Opart + (size_t)s * 2048 * 1024 + e);
        a0 += bf2f(n.x); a1 += bf2f(n.y); a2 += bf2f(n.z); a3 += bf2f(n.w);
    }
    ushort4 w;
    w.x = f2bf(a0 * inv);
    w.y = f2bf(a1 * inv);
    w.z = f2bf(a2 * inv);
    w.w = f2bf(a3 * inv);
    *(ushort4*)(ab + e) = w;
}

extern "C" void kernel_launch(void* const* d_in, const int* in_sizes, int n_in,
                              void* d_out, int out_size, void* d_ws, size_t ws_size,
                              hipStream_t stream)
{
    const float* x  = (const float*)d_in[0];
    const float* wq = (const float*)d_in[1];
    const float* wk = (const float*)d_in[2];
    const float* wv = (const float*)d_in[3];
    const float* wp = (const float*)d_in[4];

    unsigned short* xb    = (unsigned short*)d_ws;        // 2M shorts
    unsigned short* wqkvb = xb    + 2u * 1024 * 1024;     // 3M
    unsigned short* wpb   = wqkvb + 3u * 1024 * 1024;     // 1M
    unsigned short* qkv   = wpb   + 1u * 1024 * 1024;     // 6M
    unsigned short* ab    = qkv   + 2048u * 3072;         // 2M
    unsigned short* Opart = ab    + 2u * 1024 * 1024;     // 4 x 2048 x 1024 bf16
    float* Lpart = (float*)(Opart + 4u * 2048 * 1024);    // 4 x 2048 x 16 fp32

    convert_all<<<6144, 256, 0, stream>>>(x, wq, wk, wv, wp, xb, wqkvb, wpb);
    // qkv GEMM with fused RoPE: 64x128 tile -> grid (24, 32) = 768 blocks
    gemm_mfma<64, 128, 0, 1><<<dim3(24, 32), 256, 0, stream>>>(
        xb, wqkvb, qkv, 3072);
    attn_part<<<dim3(16, 16, 4), 256, 0, stream>>>(qkv, Opart, Lpart);
    combine<<<2048, 256, 0, stream>>>(Opart, Lpart, ab);
    // proj: 64x64 tile, full K, fp32 out -> grid (16, 32) = 512 blocks
    gemm_mfma<64, 64, 1, 0><<<dim3(16, 32), 256, 0, stream>>>(
        ab, wpb, d_out, 1024);
}